// Round 1
// baseline (272.471 us; speedup 1.0000x reference)
//
#include <hip/hip_runtime.h>

#define D 128
#define D4 32      // fp32 row length in float4
#define CAPH 32    // slots per half-edge-set (half-degree ~Poisson(6); P(>32) ~ 1e-16)

typedef float v4f __attribute__((ext_vector_type(4)));
typedef _Float16 h4 __attribute__((ext_vector_type(4)));   // 8-byte fp16 quad

static inline size_t align_up(size_t v, size_t a) { return (v + a - 1) & ~(a - 1); }

// ---- split-contention ELL build (at raw atomic-rate floor, unchanged) ----
// packed*: bits[63:48]=count, bits[47:0]=sum(dist) Q16.32 (exact integer add).
__global__ void fill_ell_kernel(const int* __restrict__ src,
                                const int* __restrict__ dst,
                                const float* __restrict__ dist,
                                unsigned long long* __restrict__ packedA,
                                unsigned long long* __restrict__ packedB,
                                unsigned short* __restrict__ adjA,
                                unsigned short* __restrict__ adjB,
                                int E, int Ehalf) {
  int e = blockIdx.x * blockDim.x + threadIdx.x;
  if (e >= E) return;
  int s = src[e];
  unsigned long long fx = (unsigned long long)(dist[e] * 4294967296.0f);
  unsigned long long val = (1ull << 48) | fx;
  if (e < Ehalf) {
    unsigned long long old = atomicAdd(&packedA[s], val);
    unsigned int slot = (unsigned int)(old >> 48);
    if (slot < CAPH) adjA[(size_t)s * CAPH + slot] = (unsigned short)dst[e];
  } else {
    unsigned long long old = atomicAdd(&packedB[s], val);
    unsigned int slot = (unsigned int)(old >> 48);
    if (slot < CAPH) adjB[(size_t)s * CAPH + slot] = (unsigned short)dst[e];
  }
}

// ---- base = w1*x + w2*g + w4*relu(w5*distsum), fp16, QUARTER-PLANE layout;
// ---- seed uA = fp16(x); zero dummy row N of uA/uB in every plane.
// Plane layout: h4 index = (q*(n+1) + node)*8 + lq,  q = feature-quarter 0..3,
// lq = 0..7 (each h4 = 4 features). Plane = 3.2 MB -> fits one XCD's 4MB L2.
__global__ void base_seed_kernel(const v4f* __restrict__ x4, const v4f* __restrict__ g4,
                                 const unsigned long long* __restrict__ packedA,
                                 const unsigned long long* __restrict__ packedB,
                                 const float* __restrict__ w1p, const float* __restrict__ w2p,
                                 const float* __restrict__ w4p, const float* __restrict__ w5p,
                                 h4* __restrict__ base, h4* __restrict__ uA,
                                 h4* __restrict__ uB, int n) {
  int i = blockIdx.x * blockDim.x + threadIdx.x;
  int node = i >> 5;
  int l = i & 31;            // v4f index within row (feature l*4..l*4+3)
  if (node > n) return;
  int q  = l >> 3;
  int lq = l & 7;
  size_t po = ((size_t)q * (n + 1) + node) * 8 + lq;
  if (node == n) {           // dummy zero row (clamped tail indices gather it)
    h4 z = {0, 0, 0, 0};
    uA[po] = z;
    uB[po] = z;
    return;
  }
  v4f xv = x4[(size_t)node * D4 + l];
  v4f gv = g4[l];
  unsigned long long sum = (packedA[node] & 0xFFFFFFFFFFFFull)
                         + (packedB[node] & 0xFFFFFFFFFFFFull);
  float ds = (float)sum * (1.0f / 4294967296.0f);
  float t = w5p[0] * ds;
  t = t > 0.f ? t : 0.f;
  v4f b = w1p[0] * xv + w2p[0] * gv;
  b += t * w4p[0];
  base[po] = __builtin_convertvector(b, h4);
  uA[po]   = __builtin_convertvector(xv, h4);
}

// ---- propagation, QUARTER-row (64B) XCD-partitioned planes ----
// quarter = blockIdx & 3; blockIdx%8 XCD round-robin => XCD i only ever
// touches plane (i&3) = 3.2 MB < 4 MB L2 -> random gather is L2-resident.
// 8 lanes per node-quarter; gather request = 8 x 8B contiguous = 64B aligned.
// First 8 A-gathers + first 8 B-gathers issued together (16 lines in flight).
__global__ __launch_bounds__(256) void prop_kernel(
    const h4* __restrict__ uin, const h4* __restrict__ base,
    const unsigned long long* __restrict__ packedA,
    const unsigned long long* __restrict__ packedB,
    const unsigned short* __restrict__ adjA,
    const unsigned short* __restrict__ adjB,
    const float* __restrict__ w3p,
    void* __restrict__ uout, int n, int final_relu)
{
  int q     = blockIdx.x & 3;
  int chunk = blockIdx.x >> 2;
  int group = threadIdx.x >> 3;        // 32 node-groups per block
  int lane  = threadIdx.x & 7;         // 8 lanes per node-quarter
  int node  = chunk * 32 + group;
  if (node >= n) return;

  unsigned long long pA = packedA[node];
  unsigned long long pB = packedB[node];
  int degA = (int)(pA >> 48); if (degA > CAPH) degA = CAPH;
  int degB = (int)(pB >> 48); if (degB > CAPH) degB = CAPH;

  // preload adjacency: 32 slots over 8 lanes -> 4 regs per set
  const unsigned short* rowA = adjA + (size_t)node * CAPH;
  const unsigned short* rowB = adjB + (size_t)node * CAPH;
  int a0 = rowA[lane];
  int a1 = rowA[lane + 8];
  int a2 = rowA[lane + 16];
  int a3 = rowA[lane + 24];
  int b0 = rowB[lane];
  int b1 = rowB[lane + 8];
  int b2 = rowB[lane + 16];
  int b3 = rowB[lane + 24];

  // plane base for this (quarter, lane): h4 units
  const h4* uq = uin + ((size_t)q * (n + 1)) * 8 + lane;
  size_t po = ((size_t)q * (n + 1) + node) * 8 + lane;
  v4f bb = __builtin_convertvector(base[po], v4f);   // issued early, overlaps gathers

  v4f acc0 = {0.f,0.f,0.f,0.f}, acc1 = acc0, acc2 = acc0, acc3 = acc0;

  // ---- common case: first 8 of set A and first 8 of set B, all in flight ----
  {
    int jA0 = __shfl(a0, 0, 8); jA0 = (0 < degA) ? jA0 : n;
    int jA1 = __shfl(a0, 1, 8); jA1 = (1 < degA) ? jA1 : n;
    int jA2 = __shfl(a0, 2, 8); jA2 = (2 < degA) ? jA2 : n;
    int jA3 = __shfl(a0, 3, 8); jA3 = (3 < degA) ? jA3 : n;
    int jA4 = __shfl(a0, 4, 8); jA4 = (4 < degA) ? jA4 : n;
    int jA5 = __shfl(a0, 5, 8); jA5 = (5 < degA) ? jA5 : n;
    int jA6 = __shfl(a0, 6, 8); jA6 = (6 < degA) ? jA6 : n;
    int jA7 = __shfl(a0, 7, 8); jA7 = (7 < degA) ? jA7 : n;
    int jB0 = __shfl(b0, 0, 8); jB0 = (0 < degB) ? jB0 : n;
    int jB1 = __shfl(b0, 1, 8); jB1 = (1 < degB) ? jB1 : n;
    int jB2 = __shfl(b0, 2, 8); jB2 = (2 < degB) ? jB2 : n;
    int jB3 = __shfl(b0, 3, 8); jB3 = (3 < degB) ? jB3 : n;
    int jB4 = __shfl(b0, 4, 8); jB4 = (4 < degB) ? jB4 : n;
    int jB5 = __shfl(b0, 5, 8); jB5 = (5 < degB) ? jB5 : n;
    int jB6 = __shfl(b0, 6, 8); jB6 = (6 < degB) ? jB6 : n;
    int jB7 = __shfl(b0, 7, 8); jB7 = (7 < degB) ? jB7 : n;
    h4 vA0 = uq[(size_t)jA0 * 8];
    h4 vA1 = uq[(size_t)jA1 * 8];
    h4 vA2 = uq[(size_t)jA2 * 8];
    h4 vA3 = uq[(size_t)jA3 * 8];
    h4 vA4 = uq[(size_t)jA4 * 8];
    h4 vA5 = uq[(size_t)jA5 * 8];
    h4 vA6 = uq[(size_t)jA6 * 8];
    h4 vA7 = uq[(size_t)jA7 * 8];
    h4 vB0 = uq[(size_t)jB0 * 8];
    h4 vB1 = uq[(size_t)jB1 * 8];
    h4 vB2 = uq[(size_t)jB2 * 8];
    h4 vB3 = uq[(size_t)jB3 * 8];
    h4 vB4 = uq[(size_t)jB4 * 8];
    h4 vB5 = uq[(size_t)jB5 * 8];
    h4 vB6 = uq[(size_t)jB6 * 8];
    h4 vB7 = uq[(size_t)jB7 * 8];
    acc0 += __builtin_convertvector(vA0, v4f) + __builtin_convertvector(vA1, v4f);
    acc1 += __builtin_convertvector(vA2, v4f) + __builtin_convertvector(vA3, v4f);
    acc2 += __builtin_convertvector(vA4, v4f) + __builtin_convertvector(vA5, v4f);
    acc3 += __builtin_convertvector(vA6, v4f) + __builtin_convertvector(vA7, v4f);
    acc0 += __builtin_convertvector(vB0, v4f) + __builtin_convertvector(vB1, v4f);
    acc1 += __builtin_convertvector(vB2, v4f) + __builtin_convertvector(vB3, v4f);
    acc2 += __builtin_convertvector(vB4, v4f) + __builtin_convertvector(vB5, v4f);
    acc3 += __builtin_convertvector(vB6, v4f) + __builtin_convertvector(vB7, v4f);
  }

  // ---- tails (P(deg>8) ~ 0.15 per set) ----
  for (int k = 8; k < degA; k += 8) {
    int sel = (k >= 24) ? a3 : (k >= 16) ? a2 : a1;
    int j0 = __shfl(sel, 0, 8); j0 = (k + 0 < degA) ? j0 : n;
    int j1 = __shfl(sel, 1, 8); j1 = (k + 1 < degA) ? j1 : n;
    int j2 = __shfl(sel, 2, 8); j2 = (k + 2 < degA) ? j2 : n;
    int j3 = __shfl(sel, 3, 8); j3 = (k + 3 < degA) ? j3 : n;
    int j4 = __shfl(sel, 4, 8); j4 = (k + 4 < degA) ? j4 : n;
    int j5 = __shfl(sel, 5, 8); j5 = (k + 5 < degA) ? j5 : n;
    int j6 = __shfl(sel, 6, 8); j6 = (k + 6 < degA) ? j6 : n;
    int j7 = __shfl(sel, 7, 8); j7 = (k + 7 < degA) ? j7 : n;
    h4 v0 = uq[(size_t)j0 * 8];
    h4 v1 = uq[(size_t)j1 * 8];
    h4 v2 = uq[(size_t)j2 * 8];
    h4 v3 = uq[(size_t)j3 * 8];
    h4 v4 = uq[(size_t)j4 * 8];
    h4 v5 = uq[(size_t)j5 * 8];
    h4 v6 = uq[(size_t)j6 * 8];
    h4 v7 = uq[(size_t)j7 * 8];
    acc0 += __builtin_convertvector(v0, v4f) + __builtin_convertvector(v1, v4f);
    acc1 += __builtin_convertvector(v2, v4f) + __builtin_convertvector(v3, v4f);
    acc2 += __builtin_convertvector(v4, v4f) + __builtin_convertvector(v5, v4f);
    acc3 += __builtin_convertvector(v6, v4f) + __builtin_convertvector(v7, v4f);
  }
  for (int k = 8; k < degB; k += 8) {
    int sel = (k >= 24) ? b3 : (k >= 16) ? b2 : b1;
    int j0 = __shfl(sel, 0, 8); j0 = (k + 0 < degB) ? j0 : n;
    int j1 = __shfl(sel, 1, 8); j1 = (k + 1 < degB) ? j1 : n;
    int j2 = __shfl(sel, 2, 8); j2 = (k + 2 < degB) ? j2 : n;
    int j3 = __shfl(sel, 3, 8); j3 = (k + 3 < degB) ? j3 : n;
    int j4 = __shfl(sel, 4, 8); j4 = (k + 4 < degB) ? j4 : n;
    int j5 = __shfl(sel, 5, 8); j5 = (k + 5 < degB) ? j5 : n;
    int j6 = __shfl(sel, 6, 8); j6 = (k + 6 < degB) ? j6 : n;
    int j7 = __shfl(sel, 7, 8); j7 = (k + 7 < degB) ? j7 : n;
    h4 v0 = uq[(size_t)j0 * 8];
    h4 v1 = uq[(size_t)j1 * 8];
    h4 v2 = uq[(size_t)j2 * 8];
    h4 v3 = uq[(size_t)j3 * 8];
    h4 v4 = uq[(size_t)j4 * 8];
    h4 v5 = uq[(size_t)j5 * 8];
    h4 v6 = uq[(size_t)j6 * 8];
    h4 v7 = uq[(size_t)j7 * 8];
    acc0 += __builtin_convertvector(v0, v4f) + __builtin_convertvector(v1, v4f);
    acc1 += __builtin_convertvector(v2, v4f) + __builtin_convertvector(v3, v4f);
    acc2 += __builtin_convertvector(v4, v4f) + __builtin_convertvector(v5, v4f);
    acc3 += __builtin_convertvector(v6, v4f) + __builtin_convertvector(v7, v4f);
  }

  v4f asum = (acc0 + acc1) + (acc2 + acc3);
  v4f r = bb + w3p[0] * asum;

  if (final_relu) {
    r.x = r.x > 0.f ? r.x : 0.f;
    r.y = r.y > 0.f ? r.y : 0.f;
    r.z = r.z > 0.f ? r.z : 0.f;
    r.w = r.w > 0.f ? r.w : 0.f;
    // out is row-major [N][128] f32; v4f unit (q*8+lane) = features q*32+lane*4
    __builtin_nontemporal_store(r, (v4f*)uout + (size_t)node * 32 + q * 8 + lane);
  } else {
    ((h4*)uout)[po] = __builtin_convertvector(r, h4);
  }
}

extern "C" void kernel_launch(void* const* d_in, const int* in_sizes, int n_in,
                              void* d_out, int out_size, void* d_ws, size_t ws_size,
                              hipStream_t stream) {
  const float* x    = (const float*)d_in[0];
  const float* g    = (const float*)d_in[1];
  const float* dist = (const float*)d_in[2];
  const float* w1   = (const float*)d_in[3];
  const float* w2   = (const float*)d_in[4];
  const float* w3   = (const float*)d_in[5];
  const float* w4   = (const float*)d_in[6];
  const float* w5   = (const float*)d_in[7];
  const int*   src  = (const int*)d_in[8];
  const int*   dst  = (const int*)d_in[9];

  const int N = in_sizes[0] / D;
  const int E = in_sizes[2];
  const int Ehalf = E / 2;

  // ---- workspace carve: packedA+packedB adjacent (one small memset) ----
  char* ws = (char*)d_ws;
  size_t o = 0;
  unsigned long long* packedA = (unsigned long long*)(ws + o); o += align_up((size_t)N * 8, 256);
  unsigned long long* packedB = (unsigned long long*)(ws + o);
  size_t zero_end = o + (size_t)N * 8;
  o += align_up((size_t)N * 8, 256);
  unsigned short* adjA = (unsigned short*)(ws + o); o += align_up((size_t)N * CAPH * 2, 256);
  unsigned short* adjB = (unsigned short*)(ws + o); o += align_up((size_t)N * CAPH * 2, 256);
  h4* baseB = (h4*)(ws + o); o += align_up((size_t)(N + 1) * D * 2, 256);
  h4* uA    = (h4*)(ws + o); o += align_up((size_t)(N + 1) * D * 2, 256);
  h4* uB    = (h4*)(ws + o); o += align_up((size_t)(N + 1) * D * 2, 256);
  float* out = (float*)d_out;

  hipMemsetAsync(ws, 0, zero_end, stream);   // zero packedA+packedB (0.8 MB)

  const int tb = 256;
  const int eblocks = (E + tb - 1) / tb;
  const int sthreads = (N + 1) * 32;
  const int sblocks = (sthreads + tb - 1) / tb;

  fill_ell_kernel<<<eblocks, tb, 0, stream>>>(src, dst, dist, packedA, packedB,
                                              adjA, adjB, E, Ehalf);
  base_seed_kernel<<<sblocks, tb, 0, stream>>>((const v4f*)x, (const v4f*)g,
                                               packedA, packedB,
                                               w1, w2, w4, w5, baseB, uA, uB, N);

  // grid: (node chunks of 32) x 4 feature-quarters; quarter = blockIdx & 3
  // blockIdx%8 XCD round-robin => XCD i serves only plane i&3 (3.2MB, L2-fit)
  const int chunks = (N + 31) / 32;
  const int pblocks = chunks * 4;
  prop_kernel<<<pblocks, 256, 0, stream>>>(uA, baseB, packedA, packedB, adjA, adjB, w3, uB,  N, 0);
  prop_kernel<<<pblocks, 256, 0, stream>>>(uB, baseB, packedA, packedB, adjA, adjB, w3, uA,  N, 0);
  prop_kernel<<<pblocks, 256, 0, stream>>>(uA, baseB, packedA, packedB, adjA, adjB, w3, uB,  N, 0);
  prop_kernel<<<pblocks, 256, 0, stream>>>(uB, baseB, packedA, packedB, adjA, adjB, w3, uA,  N, 0);
  prop_kernel<<<pblocks, 256, 0, stream>>>(uA, baseB, packedA, packedB, adjA, adjB, w3, out, N, 1);
}

// Round 2
// 252.628 us; speedup vs baseline: 1.0785x; 1.0785x over previous
//
#include <hip/hip_runtime.h>

#define D 128
#define D4 32      // fp32 row length in float4
#define CAPH 32    // slots per half-edge-set (half-degree ~Poisson(6); P(>32) ~ 1e-16)

typedef float v4f __attribute__((ext_vector_type(4)));
typedef _Float16 h4 __attribute__((ext_vector_type(4)));   // 8-byte fp16 quad

static inline size_t align_up(size_t v, size_t a) { return (v + a - 1) & ~(a - 1); }

// ---- split-contention ELL build (at raw atomic-rate floor, unchanged) ----
// packed*: bits[63:48]=count, bits[47:0]=sum(dist) Q16.32 (exact integer add).
__global__ void fill_ell_kernel(const int* __restrict__ src,
                                const int* __restrict__ dst,
                                const float* __restrict__ dist,
                                unsigned long long* __restrict__ packedA,
                                unsigned long long* __restrict__ packedB,
                                unsigned short* __restrict__ adjA,
                                unsigned short* __restrict__ adjB,
                                int E, int Ehalf) {
  int e = blockIdx.x * blockDim.x + threadIdx.x;
  if (e >= E) return;
  int s = src[e];
  unsigned long long fx = (unsigned long long)(dist[e] * 4294967296.0f);
  unsigned long long val = (1ull << 48) | fx;
  if (e < Ehalf) {
    unsigned long long old = atomicAdd(&packedA[s], val);
    unsigned int slot = (unsigned int)(old >> 48);
    if (slot < CAPH) adjA[(size_t)s * CAPH + slot] = (unsigned short)dst[e];
  } else {
    unsigned long long old = atomicAdd(&packedB[s], val);
    unsigned int slot = (unsigned int)(old >> 48);
    if (slot < CAPH) adjB[(size_t)s * CAPH + slot] = (unsigned short)dst[e];
  }
}

// ---- base = w1*x + w2*g + w4*relu(w5*distsum), fp16; seed uA = fp16(x);
// ---- zero dummy row N of uA/uB (clamped tail indices gather from it) ----
__global__ void base_seed_kernel(const v4f* __restrict__ x4, const v4f* __restrict__ g4,
                                 const unsigned long long* __restrict__ packedA,
                                 const unsigned long long* __restrict__ packedB,
                                 const float* __restrict__ w1p, const float* __restrict__ w2p,
                                 const float* __restrict__ w4p, const float* __restrict__ w5p,
                                 h4* __restrict__ base, h4* __restrict__ uA,
                                 h4* __restrict__ uB, int n) {
  int i = blockIdx.x * blockDim.x + threadIdx.x;
  int node = i >> 5;
  int lane = i & 31;
  if (node > n) return;
  size_t idx = (size_t)i;
  if (node == n) {           // dummy zero row
    h4 z = {0, 0, 0, 0};
    uA[idx] = z;
    uB[idx] = z;
    return;
  }
  v4f xv = x4[(size_t)node * D4 + lane];
  v4f gv = g4[lane];
  unsigned long long sum = (packedA[node] & 0xFFFFFFFFFFFFull)
                         + (packedB[node] & 0xFFFFFFFFFFFFull);
  float ds = (float)sum * (1.0f / 4294967296.0f);
  float t = w5p[0] * ds;
  t = t > 0.f ? t : 0.f;
  v4f b = w1p[0] * xv + w2p[0] * gv;
  b += t * w4p[0];
  base[idx] = __builtin_convertvector(b, h4);
  uA[idx] = __builtin_convertvector(xv, h4);
}

// ---- propagation, half-row (128B) XCD-partitioned (PROVEN layout) ----
// Block = (node chunk, feature half); half = blockIdx&1. With blockIdx%8 ->
// XCD round-robin, each XCD touches exactly ONE 128B line of any u row.
// 16 lanes per node-half, gather request = 16 x 8B contiguous = one full line.
// NEW vs baseline: first 8 A-gathers and first 8 B-gathers issued TOGETHER
// (16 lines in flight in the common deg<=8 case, was 8+8 serial); base row
// load hoisted early. Layout, traffic and line count identical to baseline.
__global__ __launch_bounds__(256) void prop_kernel(
    const h4* __restrict__ uin, const h4* __restrict__ base,
    const unsigned long long* __restrict__ packedA,
    const unsigned long long* __restrict__ packedB,
    const unsigned short* __restrict__ adjA,
    const unsigned short* __restrict__ adjB,
    const float* __restrict__ w3p,
    void* __restrict__ uout, int n, int final_relu)
{
  int half  = blockIdx.x & 1;
  int chunk = blockIdx.x >> 1;
  int group = threadIdx.x >> 4;        // 16 node-groups per block
  int lane  = threadIdx.x & 15;        // 16 lanes per node-half
  int node  = chunk * 16 + group;
  if (node >= n) return;

  unsigned long long pA = packedA[node];
  unsigned long long pB = packedB[node];
  int degA = (int)(pA >> 48); if (degA > CAPH) degA = CAPH;
  int degB = (int)(pB >> 48); if (degB > CAPH) degB = CAPH;

  // preload adjacency: set A slots 0..31 in a0/a1, set B in b0/b1
  const unsigned short* rowA = adjA + (size_t)node * CAPH;
  const unsigned short* rowB = adjB + (size_t)node * CAPH;
  int a0 = rowA[lane];
  int a1 = rowA[lane + 16];
  int b0 = rowB[lane];
  int b1 = rowB[lane + 16];

  // element offset within a row for this (half, lane): h4 units
  const h4* uh = uin + (size_t)half * 16 + lane;
  size_t idx = (size_t)node * 32 + half * 16 + lane;   // h4 / v4f units
  v4f bb = __builtin_convertvector(base[idx], v4f);    // overlaps gather chain

  v4f acc0 = {0.f,0.f,0.f,0.f}, acc1 = acc0, acc2 = acc0, acc3 = acc0;

  // ---- common case: first 8 of set A AND first 8 of set B in flight ----
  {
    int jA0 = __shfl(a0, 0, 16); jA0 = (0 < degA) ? jA0 : n;
    int jA1 = __shfl(a0, 1, 16); jA1 = (1 < degA) ? jA1 : n;
    int jA2 = __shfl(a0, 2, 16); jA2 = (2 < degA) ? jA2 : n;
    int jA3 = __shfl(a0, 3, 16); jA3 = (3 < degA) ? jA3 : n;
    int jA4 = __shfl(a0, 4, 16); jA4 = (4 < degA) ? jA4 : n;
    int jA5 = __shfl(a0, 5, 16); jA5 = (5 < degA) ? jA5 : n;
    int jA6 = __shfl(a0, 6, 16); jA6 = (6 < degA) ? jA6 : n;
    int jA7 = __shfl(a0, 7, 16); jA7 = (7 < degA) ? jA7 : n;
    int jB0 = __shfl(b0, 0, 16); jB0 = (0 < degB) ? jB0 : n;
    int jB1 = __shfl(b0, 1, 16); jB1 = (1 < degB) ? jB1 : n;
    int jB2 = __shfl(b0, 2, 16); jB2 = (2 < degB) ? jB2 : n;
    int jB3 = __shfl(b0, 3, 16); jB3 = (3 < degB) ? jB3 : n;
    int jB4 = __shfl(b0, 4, 16); jB4 = (4 < degB) ? jB4 : n;
    int jB5 = __shfl(b0, 5, 16); jB5 = (5 < degB) ? jB5 : n;
    int jB6 = __shfl(b0, 6, 16); jB6 = (6 < degB) ? jB6 : n;
    int jB7 = __shfl(b0, 7, 16); jB7 = (7 < degB) ? jB7 : n;
    h4 vA0 = uh[(size_t)jA0 * 32];
    h4 vA1 = uh[(size_t)jA1 * 32];
    h4 vA2 = uh[(size_t)jA2 * 32];
    h4 vA3 = uh[(size_t)jA3 * 32];
    h4 vA4 = uh[(size_t)jA4 * 32];
    h4 vA5 = uh[(size_t)jA5 * 32];
    h4 vA6 = uh[(size_t)jA6 * 32];
    h4 vA7 = uh[(size_t)jA7 * 32];
    h4 vB0 = uh[(size_t)jB0 * 32];
    h4 vB1 = uh[(size_t)jB1 * 32];
    h4 vB2 = uh[(size_t)jB2 * 32];
    h4 vB3 = uh[(size_t)jB3 * 32];
    h4 vB4 = uh[(size_t)jB4 * 32];
    h4 vB5 = uh[(size_t)jB5 * 32];
    h4 vB6 = uh[(size_t)jB6 * 32];
    h4 vB7 = uh[(size_t)jB7 * 32];
    acc0 += __builtin_convertvector(vA0, v4f) + __builtin_convertvector(vA1, v4f);
    acc1 += __builtin_convertvector(vA2, v4f) + __builtin_convertvector(vA3, v4f);
    acc2 += __builtin_convertvector(vA4, v4f) + __builtin_convertvector(vA5, v4f);
    acc3 += __builtin_convertvector(vA6, v4f) + __builtin_convertvector(vA7, v4f);
    acc0 += __builtin_convertvector(vB0, v4f) + __builtin_convertvector(vB1, v4f);
    acc1 += __builtin_convertvector(vB2, v4f) + __builtin_convertvector(vB3, v4f);
    acc2 += __builtin_convertvector(vB4, v4f) + __builtin_convertvector(vB5, v4f);
    acc3 += __builtin_convertvector(vB6, v4f) + __builtin_convertvector(vB7, v4f);
  }

  // ---- tails (P(deg>8) ~ 0.15 per set) ----
  for (int k = 8; k < degA; k += 8) {
    int sel = (k >= 16) ? a1 : a0;
    int j0 = __shfl(sel, (k + 0) & 15, 16); j0 = (k + 0 < degA) ? j0 : n;
    int j1 = __shfl(sel, (k + 1) & 15, 16); j1 = (k + 1 < degA) ? j1 : n;
    int j2 = __shfl(sel, (k + 2) & 15, 16); j2 = (k + 2 < degA) ? j2 : n;
    int j3 = __shfl(sel, (k + 3) & 15, 16); j3 = (k + 3 < degA) ? j3 : n;
    int j4 = __shfl(sel, (k + 4) & 15, 16); j4 = (k + 4 < degA) ? j4 : n;
    int j5 = __shfl(sel, (k + 5) & 15, 16); j5 = (k + 5 < degA) ? j5 : n;
    int j6 = __shfl(sel, (k + 6) & 15, 16); j6 = (k + 6 < degA) ? j6 : n;
    int j7 = __shfl(sel, (k + 7) & 15, 16); j7 = (k + 7 < degA) ? j7 : n;
    h4 v0 = uh[(size_t)j0 * 32];
    h4 v1 = uh[(size_t)j1 * 32];
    h4 v2 = uh[(size_t)j2 * 32];
    h4 v3 = uh[(size_t)j3 * 32];
    h4 v4 = uh[(size_t)j4 * 32];
    h4 v5 = uh[(size_t)j5 * 32];
    h4 v6 = uh[(size_t)j6 * 32];
    h4 v7 = uh[(size_t)j7 * 32];
    acc0 += __builtin_convertvector(v0, v4f) + __builtin_convertvector(v1, v4f);
    acc1 += __builtin_convertvector(v2, v4f) + __builtin_convertvector(v3, v4f);
    acc2 += __builtin_convertvector(v4, v4f) + __builtin_convertvector(v5, v4f);
    acc3 += __builtin_convertvector(v6, v4f) + __builtin_convertvector(v7, v4f);
  }
  for (int k = 8; k < degB; k += 8) {
    int sel = (k >= 16) ? b1 : b0;
    int j0 = __shfl(sel, (k + 0) & 15, 16); j0 = (k + 0 < degB) ? j0 : n;
    int j1 = __shfl(sel, (k + 1) & 15, 16); j1 = (k + 1 < degB) ? j1 : n;
    int j2 = __shfl(sel, (k + 2) & 15, 16); j2 = (k + 2 < degB) ? j2 : n;
    int j3 = __shfl(sel, (k + 3) & 15, 16); j3 = (k + 3 < degB) ? j3 : n;
    int j4 = __shfl(sel, (k + 4) & 15, 16); j4 = (k + 4 < degB) ? j4 : n;
    int j5 = __shfl(sel, (k + 5) & 15, 16); j5 = (k + 5 < degB) ? j5 : n;
    int j6 = __shfl(sel, (k + 6) & 15, 16); j6 = (k + 6 < degB) ? j6 : n;
    int j7 = __shfl(sel, (k + 7) & 15, 16); j7 = (k + 7 < degB) ? j7 : n;
    h4 v0 = uh[(size_t)j0 * 32];
    h4 v1 = uh[(size_t)j1 * 32];
    h4 v2 = uh[(size_t)j2 * 32];
    h4 v3 = uh[(size_t)j3 * 32];
    h4 v4 = uh[(size_t)j4 * 32];
    h4 v5 = uh[(size_t)j5 * 32];
    h4 v6 = uh[(size_t)j6 * 32];
    h4 v7 = uh[(size_t)j7 * 32];
    acc0 += __builtin_convertvector(v0, v4f) + __builtin_convertvector(v1, v4f);
    acc1 += __builtin_convertvector(v2, v4f) + __builtin_convertvector(v3, v4f);
    acc2 += __builtin_convertvector(v4, v4f) + __builtin_convertvector(v5, v4f);
    acc3 += __builtin_convertvector(v6, v4f) + __builtin_convertvector(v7, v4f);
  }
  v4f asum = (acc0 + acc1) + (acc2 + acc3);
  v4f r = bb + w3p[0] * asum;

  if (final_relu) {
    r.x = r.x > 0.f ? r.x : 0.f;
    r.y = r.y > 0.f ? r.y : 0.f;
    r.z = r.z > 0.f ? r.z : 0.f;
    r.w = r.w > 0.f ? r.w : 0.f;
    __builtin_nontemporal_store(r, (v4f*)uout + idx);
  } else {
    ((h4*)uout)[idx] = __builtin_convertvector(r, h4);
  }
}

extern "C" void kernel_launch(void* const* d_in, const int* in_sizes, int n_in,
                              void* d_out, int out_size, void* d_ws, size_t ws_size,
                              hipStream_t stream) {
  const float* x    = (const float*)d_in[0];
  const float* g    = (const float*)d_in[1];
  const float* dist = (const float*)d_in[2];
  const float* w1   = (const float*)d_in[3];
  const float* w2   = (const float*)d_in[4];
  const float* w3   = (const float*)d_in[5];
  const float* w4   = (const float*)d_in[6];
  const float* w5   = (const float*)d_in[7];
  const int*   src  = (const int*)d_in[8];
  const int*   dst  = (const int*)d_in[9];

  const int N = in_sizes[0] / D;
  const int E = in_sizes[2];
  const int Ehalf = E / 2;

  // ---- workspace carve: packedA+packedB adjacent (one small memset) ----
  char* ws = (char*)d_ws;
  size_t o = 0;
  unsigned long long* packedA = (unsigned long long*)(ws + o); o += align_up((size_t)N * 8, 256);
  unsigned long long* packedB = (unsigned long long*)(ws + o);
  size_t zero_end = o + (size_t)N * 8;
  o += align_up((size_t)N * 8, 256);
  unsigned short* adjA = (unsigned short*)(ws + o); o += align_up((size_t)N * CAPH * 2, 256);
  unsigned short* adjB = (unsigned short*)(ws + o); o += align_up((size_t)N * CAPH * 2, 256);
  h4* baseB = (h4*)(ws + o); o += align_up((size_t)(N + 1) * D * 2, 256);
  h4* uA    = (h4*)(ws + o); o += align_up((size_t)(N + 1) * D * 2, 256);
  h4* uB    = (h4*)(ws + o); o += align_up((size_t)(N + 1) * D * 2, 256);
  float* out = (float*)d_out;

  hipMemsetAsync(ws, 0, zero_end, stream);   // zero packedA+packedB (0.8 MB)

  const int tb = 256;
  const int eblocks = (E + tb - 1) / tb;
  const int sthreads = (N + 1) * 32;
  const int sblocks = (sthreads + tb - 1) / tb;

  fill_ell_kernel<<<eblocks, tb, 0, stream>>>(src, dst, dist, packedA, packedB,
                                              adjA, adjB, E, Ehalf);
  base_seed_kernel<<<sblocks, tb, 0, stream>>>((const v4f*)x, (const v4f*)g,
                                               packedA, packedB,
                                               w1, w2, w4, w5, baseB, uA, uB, N);

  // grid: (node chunks of 16) x 2 feature-halves; half = blockIdx & 1
  const int chunks = (N + 15) / 16;
  const int pblocks = chunks * 2;
  prop_kernel<<<pblocks, 256, 0, stream>>>(uA, baseB, packedA, packedB, adjA, adjB, w3, uB,  N, 0);
  prop_kernel<<<pblocks, 256, 0, stream>>>(uB, baseB, packedA, packedB, adjA, adjB, w3, uA,  N, 0);
  prop_kernel<<<pblocks, 256, 0, stream>>>(uA, baseB, packedA, packedB, adjA, adjB, w3, uB,  N, 0);
  prop_kernel<<<pblocks, 256, 0, stream>>>(uB, baseB, packedA, packedB, adjA, adjB, w3, uA,  N, 0);
  prop_kernel<<<pblocks, 256, 0, stream>>>(uA, baseB, packedA, packedB, adjA, adjB, w3, out, N, 1);
}